// Round 3
// baseline (409.079 us; speedup 1.0000x reference)
//
#include <hip/hip_runtime.h>
#include <math.h>

#define BB 8
#define NN 2048
#define SS 16
#define CC 32
#define DD 128

typedef unsigned short u16;
typedef __attribute__((ext_vector_type(8))) short bf16x8;
typedef __attribute__((ext_vector_type(4))) float f32x4;

__device__ inline u16 f2bf(float f) {
    union { float f; unsigned u; } c; c.f = f;
    unsigned r = c.u + 0x7fff + ((c.u >> 16) & 1);   // round-to-nearest-even
    return (u16)(r >> 16);
}
__device__ inline float bf2f(u16 h) {
    union { unsigned u; float f; } c; c.u = ((unsigned)h) << 16;
    return c.f;
}
__device__ inline float clamp01(float v) { return fminf(fmaxf(v, 0.f), 1.f); }

// ---------------- K1: masked temporal mean pooling ----------------
__global__ __launch_bounds__(256) void pool_kernel(const float* __restrict__ X,
                                                   const float* __restrict__ M,
                                                   float* __restrict__ x) {
    int g = blockIdx.x * 256 + threadIdx.x;       // over B*N*C = 524288
    int c = g & (CC - 1);
    int bn = g >> 5;
    const float* mrow = M + (size_t)bn * SS;
    const float* xrow = X + (size_t)bn * SS * CC + c;
    float msum = 0.f, acc = 0.f;
#pragma unroll
    for (int s = 0; s < SS; ++s) {
        float mv = mrow[s];
        msum += mv;
        acc = fmaf(xrow[s * CC], mv, acc);
    }
    x[g] = acc / fmaxf(msum, 1.0f);
}

// ---------------- K2: fold projections: Wpq = W_proj@Wq, Wpk = W_proj@Wk ----
__global__ __launch_bounds__(256) void wcomb_kernel(const float* __restrict__ Wproj,
                                                    const float* __restrict__ Wq,
                                                    const float* __restrict__ Wk,
                                                    float* __restrict__ Wpq,
                                                    float* __restrict__ Wpk) {
    int g = blockIdx.x * 256 + threadIdx.x;       // over 2*32*128 = 8192
    int d = g & 127;
    int c = (g >> 7) & 31;
    int mat = g >> 12;
    const float* Wt = mat ? Wk : Wq;
    float acc = 0.f;
#pragma unroll 4
    for (int e = 0; e < DD; ++e)
        acc = fmaf(Wproj[c * DD + e], Wt[e * DD + d], acc);
    (mat ? Wpk : Wpq)[c * DD + d] = acc;
}

// ---------------- K2b: WlT[d'][d] = bf16(W_lin[d][d']) ---------------------
__global__ __launch_bounds__(256) void wlt_kernel(const float* __restrict__ Wl,
                                                  u16* __restrict__ WlT) {
    int g = blockIdx.x * 256 + threadIdx.x;       // 16384
    int dp = g >> 7, d = g & 127;
    WlT[dp * DD + d] = f2bf(Wl[d * DD + dp]);
}

// ---------------- K2c: bias precompute: lgm (f32), am (bf16) ---------------
__global__ __launch_bounds__(256) void bias_prep_kernel(const float* __restrict__ Astat,
                                                        const int* __restrict__ Mm,
                                                        float* __restrict__ lgm,
                                                        u16* __restrict__ am) {
    size_t g = (size_t)blockIdx.x * 256 + threadIdx.x;   // 4194304
    float a = Astat[g];
    int e = Mm[g];
    float p = fminf(fmaxf(a, 1e-3f), 1.f - 1e-3f);
    float lg = __logf(p / (1.f - p));             // ETA = 1.0
    lgm[g] = e ? lg : -1e30f;
    am[g] = e ? f2bf(a) : (u16)0;
}

// ---------------- K3: Hn/Q/K, emitted bf16 (Q pre-scaled; Hn^T) ------------
__global__ __launch_bounds__(256) void proj3_kernel(const float* __restrict__ x,
                                                    const float* __restrict__ Wproj,
                                                    const float* __restrict__ Wpq,
                                                    const float* __restrict__ Wpk,
                                                    u16* __restrict__ HnT,
                                                    u16* __restrict__ Qb,
                                                    u16* __restrict__ Kb) {
    __shared__ float wp[CC * DD], wq[CC * DD], wk[CC * DD];
    __shared__ float xs[CC * 36];
    int t = threadIdx.x;
    for (int i = t; i < CC * DD; i += 256) {
        wp[i] = Wproj[i];
        wq[i] = Wpq[i];
        wk[i] = Wpk[i];
    }
    int rbase = blockIdx.x * 32;
    for (int i = t; i < 32 * CC; i += 256) {
        int row = i >> 5, c = i & 31;
        xs[c * 36 + row] = x[(size_t)(rbase + row) * CC + c];
    }
    __syncthreads();

    int col = t & 127;
    int g = t >> 7;
    float ah[16], aq[16], ak[16];
#pragma unroll
    for (int i = 0; i < 16; ++i) { ah[i] = 0.f; aq[i] = 0.f; ak[i] = 0.f; }

#pragma unroll 4
    for (int k = 0; k < CC; ++k) {
        float wpv = wp[k * DD + col], wqv = wq[k * DD + col], wkv = wk[k * DD + col];
        const float4* xp = (const float4*)&xs[k * 36 + g * 16];
        float4 a0 = xp[0], a1 = xp[1], a2 = xp[2], a3 = xp[3];
        float xv[16] = {a0.x, a0.y, a0.z, a0.w, a1.x, a1.y, a1.z, a1.w,
                        a2.x, a2.y, a2.z, a2.w, a3.x, a3.y, a3.z, a3.w};
#pragma unroll
        for (int i = 0; i < 16; ++i) {
            ah[i] = fmaf(xv[i], wpv, ah[i]);
            aq[i] = fmaf(xv[i], wqv, aq[i]);
            ak[i] = fmaf(xv[i], wkv, ak[i]);
        }
    }
    const float scale = 0.08838834764831845f;     // 1/sqrt(128) folded into Q
#pragma unroll
    for (int i = 0; i < 16; ++i) {
        size_t row = (size_t)(rbase + g * 16 + i);
        Qb[row * DD + col] = f2bf(aq[i] * scale);
        Kb[row * DD + col] = f2bf(ak[i]);
    }
    int b = rbase >> 11;
    int n0 = (rbase & (NN - 1)) + g * 16;
    u16* hp = HnT + (size_t)b * DD * NN + (size_t)col * NN + n0;
    unsigned pk[8];
#pragma unroll
    for (int i = 0; i < 8; ++i)
        pk[i] = (unsigned)f2bf(ah[2 * i]) | ((unsigned)f2bf(ah[2 * i + 1]) << 16);
    *(uint4*)&hp[0] = make_uint4(pk[0], pk[1], pk[2], pk[3]);
    *(uint4*)&hp[8] = make_uint4(pk[4], pk[5], pk[6], pk[7]);
}

// ---------------- K4: fused logits+softmax+fuse+renorm (2-pass recompute) ---
// Block: 32 rows x full 2048 cols of one batch. No max-subtraction needed:
// |logit| <= ~7.5 (clamped bias +- 6.91, |qk/sqrt(D)| < ~0.6) -> exp safe.
#define LQT 136
__global__ __launch_bounds__(256) void attn_fused_kernel(
        const u16* __restrict__ Qb, const u16* __restrict__ Kb,
        const float* __restrict__ lgm, const u16* __restrict__ am,
        const float* __restrict__ rel,
        float* __restrict__ Af, u16* __restrict__ Afb) {
    __shared__ u16 Qs[32 * LQT];
    __shared__ u16 Ks[128 * LQT];
    __shared__ float redE[4 * 32], redR[4 * 32], redA[4 * 32];
    __shared__ float2 ABs[32];
    int b = blockIdx.y;
    int R0 = blockIdx.x * 32;
    int t = threadIdx.x;
    int lane = t & 63, w = t >> 6;               // w = col-group (0..3)
    int q = lane >> 4, r16 = lane & 15;

    // stage Q rows once (32 x 128 bf16)
    {
        const u16* Qg = Qb + ((size_t)b * NN + R0) * DD;
#pragma unroll
        for (int rep = 0; rep < 2; ++rep) {
            int e = rep * 256 + t;               // 512 uint4
            int row = e >> 4, seg = e & 15;
            *(uint4*)&Qs[row * LQT + seg * 8] = *(const uint4*)&Qg[row * DD + seg * 8];
        }
    }
    const u16* Kg = Kb + (size_t)b * NN * DD;
    float ER[2][4], LR[2][4], LA[2][4], al[2][4], be[2][4];
#pragma unroll
    for (int i = 0; i < 2; ++i)
#pragma unroll
        for (int r = 0; r < 4; ++r) {
            ER[i][r] = 0.f; LR[i][r] = 0.f; LA[i][r] = 0.f;
            al[i][r] = 0.f; be[i][r] = 0.f;
        }

    for (int pass = 0; pass < 2; ++pass) {
        for (int ct = 0; ct < 16; ++ct) {
            __syncthreads();
#pragma unroll
            for (int rep = 0; rep < 8; ++rep) {   // stage K tile: 128 cols x 128 k
                int e = rep * 256 + t;
                int colr = e >> 4, seg = e & 15;
                *(uint4*)&Ks[colr * LQT + seg * 8] =
                    *(const uint4*)&Kg[(size_t)(ct * 128 + colr) * DD + seg * 8];
            }
            __syncthreads();
            f32x4 acc[2][2];
#pragma unroll
            for (int i = 0; i < 2; ++i)
#pragma unroll
                for (int j = 0; j < 2; ++j)
                    acc[i][j] = (f32x4){0.f, 0.f, 0.f, 0.f};
#pragma unroll
            for (int ks = 0; ks < 4; ++ks) {
                int ko = ks * 32 + q * 8;
                bf16x8 a0 = *(const bf16x8*)&Qs[r16 * LQT + ko];
                bf16x8 a1 = *(const bf16x8*)&Qs[(16 + r16) * LQT + ko];
                bf16x8 b0 = *(const bf16x8*)&Ks[(w * 32 + r16) * LQT + ko];
                bf16x8 b1 = *(const bf16x8*)&Ks[(w * 32 + 16 + r16) * LQT + ko];
                acc[0][0] = __builtin_amdgcn_mfma_f32_16x16x32_bf16(a0, b0, acc[0][0], 0, 0, 0);
                acc[0][1] = __builtin_amdgcn_mfma_f32_16x16x32_bf16(a0, b1, acc[0][1], 0, 0, 0);
                acc[1][0] = __builtin_amdgcn_mfma_f32_16x16x32_bf16(a1, b0, acc[1][0], 0, 0, 0);
                acc[1][1] = __builtin_amdgcn_mfma_f32_16x16x32_bf16(a1, b1, acc[1][1], 0, 0, 0);
            }
            int m0 = ct * 128 + w * 32;
            float rm0 = clamp01(rel[b * NN + m0 + r16]);
            float rm1 = clamp01(rel[b * NN + m0 + 16 + r16]);
#pragma unroll
            for (int i = 0; i < 2; ++i)
#pragma unroll
                for (int r = 0; r < 4; ++r) {
                    int n = R0 + i * 16 + q * 4 + r;
                    const float* lrow = lgm + (size_t)n * NN + m0;
                    const u16* arow = am + (size_t)n * NN + m0;
                    float lg0 = lrow[r16], lg1 = lrow[16 + r16];
                    float a0 = bf2f(arow[r16]), a1 = bf2f(arow[16 + r16]);
                    float e0 = __expf(acc[i][0][r] + lg0);   // masked: lg=-1e30 -> 0
                    float e1 = __expf(acc[i][1][r] + lg1);
                    if (pass == 0) {
                        ER[i][r] += e0 + e1;
                        LR[i][r] = fmaf(e0, rm0, fmaf(e1, rm1, LR[i][r]));
                        LA[i][r] = fmaf(a0, rm0, fmaf(a1, rm1, LA[i][r]));
                    } else {
                        float v0 = rm0 * fmaf(e0, al[i][r], a0 * be[i][r]);
                        float v1 = rm1 * fmaf(e1, al[i][r], a1 * be[i][r]);
                        size_t o = (size_t)b * NN * NN + (size_t)n * NN + m0;
                        Af[o + r16] = v0;
                        Af[o + 16 + r16] = v1;
                        Afb[o + r16] = f2bf(v0);
                        Afb[o + 16 + r16] = f2bf(v1);
                    }
                }
        }
        if (pass == 0) {
            // reduce 3 stats over the 16-lane col groups
#pragma unroll
            for (int i = 0; i < 2; ++i)
#pragma unroll
                for (int r = 0; r < 4; ++r) {
                    float e = ER[i][r], lr = LR[i][r], la = LA[i][r];
#pragma unroll
                    for (int off = 1; off < 16; off <<= 1) {
                        e += __shfl_xor(e, off);
                        lr += __shfl_xor(lr, off);
                        la += __shfl_xor(la, off);
                    }
                    ER[i][r] = e; LR[i][r] = lr; LA[i][r] = la;
                }
            if (r16 == 0) {
#pragma unroll
                for (int i = 0; i < 2; ++i)
#pragma unroll
                    for (int r = 0; r < 4; ++r) {
                        int row = i * 16 + q * 4 + r;
                        redE[w * 32 + row] = ER[i][r];
                        redR[w * 32 + row] = LR[i][r];
                        redA[w * 32 + row] = LA[i][r];
                    }
            }
            __syncthreads();
            if (t < 32) {
                float es = redE[t] + redE[32 + t] + redE[64 + t] + redE[96 + t];
                float lr = redR[t] + redR[32 + t] + redR[64 + t] + redR[96 + t];
                float la = redA[t] + redA[32 + t] + redA[64 + t] + redA[96 + t];
                float rn = clamp01(rel[b * NN + R0 + t]);
                float inv = 1.f / es;             // es > 0 (diag edge kept)
                float fsum = rn * (0.6f * lr * inv + 0.4f * la);
                float nrm = 1.f / (fsum + 1e-8f);
                ABs[t] = make_float2(0.6f * inv * rn * nrm, 0.4f * rn * nrm);
            }
            __syncthreads();
#pragma unroll
            for (int i = 0; i < 2; ++i)
#pragma unroll
                for (int r = 0; r < 4; ++r) {
                    float2 ab = ABs[i * 16 + q * 4 + r];
                    al[i][r] = ab.x;
                    be[i][r] = ab.y;
                }
        }
    }
}

// ---------------- K5: H=Afuse@Hn -> @W_lin -> relu -> LN1 -> LN2 -----------
#define LBT 72
#define LWT 136
__global__ __launch_bounds__(256) void prop_fused_kernel(
        const u16* __restrict__ Afb, const u16* __restrict__ HnT,
        const u16* __restrict__ WlT,
        const float* __restrict__ s1, const float* __restrict__ b1,
        const float* __restrict__ s2, const float* __restrict__ b2,
        float* __restrict__ out) {
    __shared__ u16 As[32 * LBT];
    __shared__ u16 Bs[128 * LBT];
    __shared__ u16 Ws[128 * LWT];
    __shared__ u16 Hs[32 * LWT];
    __shared__ float redS[4 * 32], redQ[4 * 32];
    __shared__ float2 MV[32];
    int b = blockIdx.y;
    int R0 = blockIdx.x * 32;
    int t = threadIdx.x;
    int lane = t & 63, w = t >> 6, q = lane >> 4, r16 = lane & 15;

    // stage WlT (128 x 128 bf16)
#pragma unroll
    for (int rep = 0; rep < 8; ++rep) {
        int e = rep * 256 + t;
        int dp = e >> 4, seg = e & 15;
        *(uint4*)&Ws[dp * LWT + seg * 8] = *(const uint4*)&WlT[dp * DD + seg * 8];
    }

    f32x4 acc[2][2];
#pragma unroll
    for (int i = 0; i < 2; ++i)
#pragma unroll
        for (int j = 0; j < 2; ++j)
            acc[i][j] = (f32x4){0.f, 0.f, 0.f, 0.f};

    const u16* Ag = Afb + ((size_t)b * NN + R0) * NN;
    const u16* Bg = HnT + (size_t)b * DD * NN;
    for (int kc = 0; kc < NN; kc += 64) {
        __syncthreads();
        {
            int row = t >> 3, seg = t & 7;        // 256 uint4 = 32x8
            *(uint4*)&As[row * LBT + seg * 8] =
                *(const uint4*)&Ag[(size_t)row * NN + kc + seg * 8];
        }
#pragma unroll
        for (int rep = 0; rep < 4; ++rep) {       // 1024 uint4 = 128x8
            int e = rep * 256 + t;
            int d = e >> 3, seg = e & 7;
            *(uint4*)&Bs[d * LBT + seg * 8] =
                *(const uint4*)&Bg[(size_t)d * NN + kc + seg * 8];
        }
        __syncthreads();
#pragma unroll
        for (int ks = 0; ks < 2; ++ks) {
            int ko = ks * 32 + q * 8;
            bf16x8 a0 = *(const bf16x8*)&As[r16 * LBT + ko];
            bf16x8 a1 = *(const bf16x8*)&As[(16 + r16) * LBT + ko];
            bf16x8 b0 = *(const bf16x8*)&Bs[(w * 32 + r16) * LBT + ko];
            bf16x8 b1v = *(const bf16x8*)&Bs[(w * 32 + 16 + r16) * LBT + ko];
            acc[0][0] = __builtin_amdgcn_mfma_f32_16x16x32_bf16(a0, b0, acc[0][0], 0, 0, 0);
            acc[0][1] = __builtin_amdgcn_mfma_f32_16x16x32_bf16(a0, b1v, acc[0][1], 0, 0, 0);
            acc[1][0] = __builtin_amdgcn_mfma_f32_16x16x32_bf16(a1, b0, acc[1][0], 0, 0, 0);
            acc[1][1] = __builtin_amdgcn_mfma_f32_16x16x32_bf16(a1, b1v, acc[1][1], 0, 0, 0);
        }
    }
    // H tile -> LDS as bf16 (A operand of second GEMM)
#pragma unroll
    for (int i = 0; i < 2; ++i)
#pragma unroll
        for (int j = 0; j < 2; ++j)
#pragma unroll
            for (int r = 0; r < 4; ++r)
                Hs[(i * 16 + q * 4 + r) * LWT + w * 32 + j * 16 + r16] = f2bf(acc[i][j][r]);
    __syncthreads();

    f32x4 c2[2][2];
#pragma unroll
    for (int i = 0; i < 2; ++i)
#pragma unroll
        for (int j = 0; j < 2; ++j)
            c2[i][j] = (f32x4){0.f, 0.f, 0.f, 0.f};
#pragma unroll
    for (int ks = 0; ks < 4; ++ks) {
        int ko = ks * 32 + q * 8;
        bf16x8 a0 = *(const bf16x8*)&Hs[r16 * LWT + ko];
        bf16x8 a1 = *(const bf16x8*)&Hs[(16 + r16) * LWT + ko];
        bf16x8 b0 = *(const bf16x8*)&Ws[(w * 32 + r16) * LWT + ko];
        bf16x8 b1v = *(const bf16x8*)&Ws[(w * 32 + 16 + r16) * LWT + ko];
        c2[0][0] = __builtin_amdgcn_mfma_f32_16x16x32_bf16(a0, b0, c2[0][0], 0, 0, 0);
        c2[0][1] = __builtin_amdgcn_mfma_f32_16x16x32_bf16(a0, b1v, c2[0][1], 0, 0, 0);
        c2[1][0] = __builtin_amdgcn_mfma_f32_16x16x32_bf16(a1, b0, c2[1][0], 0, 0, 0);
        c2[1][1] = __builtin_amdgcn_mfma_f32_16x16x32_bf16(a1, b1v, c2[1][1], 0, 0, 0);
    }
    // relu
    float v[2][2][4];
#pragma unroll
    for (int i = 0; i < 2; ++i)
#pragma unroll
        for (int j = 0; j < 2; ++j)
#pragma unroll
            for (int r = 0; r < 4; ++r)
                v[i][j][r] = fmaxf(c2[i][j][r], 0.f);

    int c0 = w * 32 + r16, c1 = w * 32 + 16 + r16;
    float s1c0 = s1[c0], s1c1 = s1[c1], b1c0 = b1[c0], b1c1 = b1[c1];
    float s2c0 = s2[c0], s2c1 = s2[c1], b2c0 = b2[c0], b2c1 = b2[c1];

    // ---- LN1 reduction ----
#pragma unroll
    for (int i = 0; i < 2; ++i)
#pragma unroll
        for (int r = 0; r < 4; ++r) {
            float s = v[i][0][r] + v[i][1][r];
            float qq = v[i][0][r] * v[i][0][r] + v[i][1][r] * v[i][1][r];
#pragma unroll
            for (int off = 1; off < 16; off <<= 1) {
                s += __shfl_xor(s, off);
                qq += __shfl_xor(qq, off);
            }
            if (r16 == 0) {
                int row = i * 16 + q * 4 + r;
                redS[w * 32 + row] = s;
                redQ[w * 32 + row] = qq;
            }
        }
    __syncthreads();
    if (t < 32) {
        float s = redS[t] + redS[32 + t] + redS[64 + t] + redS[96 + t];
        float qq = redQ[t] + redQ[32 + t] + redQ[64 + t] + redQ[96 + t];
        float mu = s * (1.f / 128.f);
        float var = qq * (1.f / 128.f) - mu * mu;
        MV[t] = make_float2(mu, 1.f / sqrtf(var + 1e-5f));
    }
    __syncthreads();
    float y[2][2][4];
#pragma unroll
    for (int i = 0; i < 2; ++i)
#pragma unroll
        for (int r = 0; r < 4; ++r) {
            float2 mv = MV[i * 16 + q * 4 + r];
            y[i][0][r] = (v[i][0][r] - mv.x) * mv.y * s1c0 + b1c0;
            y[i][1][r] = (v[i][1][r] - mv.x) * mv.y * s1c1 + b1c1;
        }
    // ---- LN2 reduction ----
#pragma unroll
    for (int i = 0; i < 2; ++i)
#pragma unroll
        for (int r = 0; r < 4; ++r) {
            float s = y[i][0][r] + y[i][1][r];
            float qq = y[i][0][r] * y[i][0][r] + y[i][1][r] * y[i][1][r];
#pragma unroll
            for (int off = 1; off < 16; off <<= 1) {
                s += __shfl_xor(s, off);
                qq += __shfl_xor(qq, off);
            }
            if (r16 == 0) {
                int row = i * 16 + q * 4 + r;
                redS[w * 32 + row] = s;
                redQ[w * 32 + row] = qq;
            }
        }
    __syncthreads();
    if (t < 32) {
        float s = redS[t] + redS[32 + t] + redS[64 + t] + redS[96 + t];
        float qq = redQ[t] + redQ[32 + t] + redQ[64 + t] + redQ[96 + t];
        float mu = s * (1.f / 128.f);
        float var = qq * (1.f / 128.f) - mu * mu;
        MV[t] = make_float2(mu, 1.f / sqrtf(var + 1e-5f));
    }
    __syncthreads();
#pragma unroll
    for (int i = 0; i < 2; ++i)
#pragma unroll
        for (int r = 0; r < 4; ++r) {
            float2 mv = MV[i * 16 + q * 4 + r];
            size_t o = (size_t)(b * NN + R0 + i * 16 + q * 4 + r) * DD;
            out[o + c0] = (y[i][0][r] - mv.x) * mv.y * s2c0 + b2c0;
            out[o + c1] = (y[i][1][r] - mv.x) * mv.y * s2c1 + b2c1;
        }
}

extern "C" void kernel_launch(void* const* d_in, const int* in_sizes, int n_in,
                              void* d_out, int out_size, void* d_ws, size_t ws_size,
                              hipStream_t stream) {
    const float* X = (const float*)d_in[0];
    const float* Msk = (const float*)d_in[1];
    const float* Astat = (const float*)d_in[2];
    const int* Mm = (const int*)d_in[3];
    const float* rel = (const float*)d_in[4];
    const float* Wproj = (const float*)d_in[5];
    const float* Wq = (const float*)d_in[6];
    const float* Wk = (const float*)d_in[7];
    const float* Wlin = (const float*)d_in[8];
    const float* s1 = (const float*)d_in[9];
    const float* b1 = (const float*)d_in[10];
    const float* s2 = (const float*)d_in[11];
    const float* b2 = (const float*)d_in[12];

    float* outMain = (float*)d_out;                       // (B,N,D)
    float* Afuse = outMain + (size_t)BB * NN * DD;        // (B,N,N)

    float* w_ = (float*)d_ws;
    float* x = w_;                                        // 524288 f
    float* Wpq = w_ + 524288;                             // 4096 f
    float* Wpk = w_ + 528384;                             // 4096 f
    u16* WlT = (u16*)(w_ + 532480);                       // 16384 u16
    u16* Qb = (u16*)(w_ + 540672);                        // 4 MB
    u16* Kb = (u16*)(w_ + 1589248);
    u16* HnT = (u16*)(w_ + 2637824);
    float* lgm = w_ + 3686400;                            // 16.8 MB
    u16* am = (u16*)(w_ + 7880704);                       // 8.4 MB
    u16* Afb = (u16*)(w_ + 9977856);                      // 67 MB

    pool_kernel<<<dim3(2048), dim3(256), 0, stream>>>(X, Msk, x);
    wcomb_kernel<<<dim3(32), dim3(256), 0, stream>>>(Wproj, Wq, Wk, Wpq, Wpk);
    wlt_kernel<<<dim3(64), dim3(256), 0, stream>>>(Wlin, WlT);
    bias_prep_kernel<<<dim3(16384), dim3(256), 0, stream>>>(Astat, Mm, lgm, am);
    proj3_kernel<<<dim3(512), dim3(256), 0, stream>>>(x, Wproj, Wpq, Wpk, HnT, Qb, Kb);

    attn_fused_kernel<<<dim3(64, 8), dim3(256), 0, stream>>>(
        Qb, Kb, lgm, am, rel, Afuse, Afb);

    prop_fused_kernel<<<dim3(64, 8), dim3(256), 0, stream>>>(
        Afb, HnT, WlT, s1, b1, s2, b2, outMain);
}

// Round 4
// 374.268 us; speedup vs baseline: 1.0930x; 1.0930x over previous
//
#include <hip/hip_runtime.h>
#include <math.h>

#define BB 8
#define NN 2048
#define SS 16
#define CC 32
#define DD 128

typedef unsigned short u16;
typedef __attribute__((ext_vector_type(8))) short bf16x8;
typedef __attribute__((ext_vector_type(4))) float f32x4;

__device__ inline u16 f2bf(float f) {
    union { float f; unsigned u; } c; c.f = f;
    unsigned r = c.u + 0x7fff + ((c.u >> 16) & 1);   // round-to-nearest-even
    return (u16)(r >> 16);
}
__device__ inline float bf2f(u16 h) {
    union { unsigned u; float f; } c; c.u = ((unsigned)h) << 16;
    return c.f;
}
__device__ inline u16 f2h(float f) {
    union { _Float16 h; u16 u; } c; c.h = (_Float16)f;
    return c.u;
}
__device__ inline float h2f(u16 u) {
    union { _Float16 h; u16 v; } c; c.v = u;
    return (float)c.h;
}
__device__ inline float clamp01(float v) { return fminf(fmaxf(v, 0.f), 1.f); }

// ---------------- K1: masked temporal mean pooling ----------------
__global__ __launch_bounds__(256) void pool_kernel(const float* __restrict__ X,
                                                   const float* __restrict__ M,
                                                   float* __restrict__ x) {
    int g = blockIdx.x * 256 + threadIdx.x;       // over B*N*C = 524288
    int c = g & (CC - 1);
    int bn = g >> 5;
    const float* mrow = M + (size_t)bn * SS;
    const float* xrow = X + (size_t)bn * SS * CC + c;
    float msum = 0.f, acc = 0.f;
#pragma unroll
    for (int s = 0; s < SS; ++s) {
        float mv = mrow[s];
        msum += mv;
        acc = fmaf(xrow[s * CC], mv, acc);
    }
    x[g] = acc / fmaxf(msum, 1.0f);
}

// ---------------- K2: fold projections: Wpq = W_proj@Wq, Wpk = W_proj@Wk ----
__global__ __launch_bounds__(256) void wcomb_kernel(const float* __restrict__ Wproj,
                                                    const float* __restrict__ Wq,
                                                    const float* __restrict__ Wk,
                                                    float* __restrict__ Wpq,
                                                    float* __restrict__ Wpk) {
    int g = blockIdx.x * 256 + threadIdx.x;       // over 2*32*128 = 8192
    int d = g & 127;
    int c = (g >> 7) & 31;
    int mat = g >> 12;
    const float* Wt = mat ? Wk : Wq;
    float acc = 0.f;
#pragma unroll 4
    for (int e = 0; e < DD; ++e)
        acc = fmaf(Wproj[c * DD + e], Wt[e * DD + d], acc);
    (mat ? Wpk : Wpq)[c * DD + d] = acc;
}

// ---------------- K2b: WlT[d'][d] = bf16(W_lin[d][d']) ---------------------
__global__ __launch_bounds__(256) void wlt_kernel(const float* __restrict__ Wl,
                                                  u16* __restrict__ WlT) {
    int g = blockIdx.x * 256 + threadIdx.x;       // 16384
    int dp = g >> 7, d = g & 127;
    WlT[dp * DD + d] = f2bf(Wl[d * DD + dp]);
}

// ---------------- K2c: bias precompute: lgh (f16, -inf masked), am (bf16) ---
__global__ __launch_bounds__(256) void bias_prep_kernel(const float* __restrict__ Astat,
                                                        const int* __restrict__ Mm,
                                                        u16* __restrict__ lgh,
                                                        u16* __restrict__ am) {
    size_t g = ((size_t)blockIdx.x * 256 + threadIdx.x) * 4;   // 4194304 total
    float4 a4 = *(const float4*)&Astat[g];
    int4 m4 = *(const int4*)&Mm[g];
    float a[4] = {a4.x, a4.y, a4.z, a4.w};
    int mm[4] = {m4.x, m4.y, m4.z, m4.w};
    ushort4 lo, ao;
    u16 lg[4], ab[4];
#pragma unroll
    for (int j = 0; j < 4; ++j) {
        float p = fminf(fmaxf(a[j], 1e-3f), 1.f - 1e-3f);
        float l = __logf(p / (1.f - p));          // ETA = 1.0
        lg[j] = mm[j] ? f2h(l) : (u16)0xFC00;     // -inf f16 when masked
        ab[j] = mm[j] ? f2bf(a[j]) : (u16)0;
    }
    lo.x = lg[0]; lo.y = lg[1]; lo.z = lg[2]; lo.w = lg[3];
    ao.x = ab[0]; ao.y = ab[1]; ao.z = ab[2]; ao.w = ab[3];
    *(ushort4*)&lgh[g] = lo;
    *(ushort4*)&am[g] = ao;
}

// ---------------- K3: Hn/Q/K, emitted bf16 (Q pre-scaled; Hn^T) ------------
__global__ __launch_bounds__(256) void proj3_kernel(const float* __restrict__ x,
                                                    const float* __restrict__ Wproj,
                                                    const float* __restrict__ Wpq,
                                                    const float* __restrict__ Wpk,
                                                    u16* __restrict__ HnT,
                                                    u16* __restrict__ Qb,
                                                    u16* __restrict__ Kb) {
    __shared__ float wp[CC * DD], wq[CC * DD], wk[CC * DD];
    __shared__ float xs[CC * 36];
    int t = threadIdx.x;
    for (int i = t; i < CC * DD; i += 256) {
        wp[i] = Wproj[i];
        wq[i] = Wpq[i];
        wk[i] = Wpk[i];
    }
    int rbase = blockIdx.x * 32;
    for (int i = t; i < 32 * CC; i += 256) {
        int row = i >> 5, c = i & 31;
        xs[c * 36 + row] = x[(size_t)(rbase + row) * CC + c];
    }
    __syncthreads();

    int col = t & 127;
    int g = t >> 7;
    float ah[16], aq[16], ak[16];
#pragma unroll
    for (int i = 0; i < 16; ++i) { ah[i] = 0.f; aq[i] = 0.f; ak[i] = 0.f; }

#pragma unroll 4
    for (int k = 0; k < CC; ++k) {
        float wpv = wp[k * DD + col], wqv = wq[k * DD + col], wkv = wk[k * DD + col];
        const float4* xp = (const float4*)&xs[k * 36 + g * 16];
        float4 a0 = xp[0], a1 = xp[1], a2 = xp[2], a3 = xp[3];
        float xv[16] = {a0.x, a0.y, a0.z, a0.w, a1.x, a1.y, a1.z, a1.w,
                        a2.x, a2.y, a2.z, a2.w, a3.x, a3.y, a3.z, a3.w};
#pragma unroll
        for (int i = 0; i < 16; ++i) {
            ah[i] = fmaf(xv[i], wpv, ah[i]);
            aq[i] = fmaf(xv[i], wqv, aq[i]);
            ak[i] = fmaf(xv[i], wkv, ak[i]);
        }
    }
    const float scale = 0.08838834764831845f;     // 1/sqrt(128) folded into Q
#pragma unroll
    for (int i = 0; i < 16; ++i) {
        size_t row = (size_t)(rbase + g * 16 + i);
        Qb[row * DD + col] = f2bf(aq[i] * scale);
        Kb[row * DD + col] = f2bf(ak[i]);
    }
    int b = rbase >> 11;
    int n0 = (rbase & (NN - 1)) + g * 16;
    u16* hp = HnT + (size_t)b * DD * NN + (size_t)col * NN + n0;
    unsigned pk[8];
#pragma unroll
    for (int i = 0; i < 8; ++i)
        pk[i] = (unsigned)f2bf(ah[2 * i]) | ((unsigned)f2bf(ah[2 * i + 1]) << 16);
    *(uint4*)&hp[0] = make_uint4(pk[0], pk[1], pk[2], pk[3]);
    *(uint4*)&hp[8] = make_uint4(pk[4], pk[5], pk[6], pk[7]);
}

// ---------------- K4: stats — QK^T tile, e=exp(dot+lg) -> Ebuf, row partials
// Block: 32 rows x 512 cols. grid (cs=4, rt=64, b=8) = 2048 blocks.
// No max-subtraction: |logit| <= ~7.5 (bias clamped +-6.91), exp safe in fp32.
#define LQT 136
__global__ __launch_bounds__(256) void stats_kernel(
        const u16* __restrict__ Qb, const u16* __restrict__ Kb,
        const u16* __restrict__ lgh, const u16* __restrict__ am,
        const float* __restrict__ rel,
        u16* __restrict__ Ebuf, float* __restrict__ part) {
    __shared__ u16 Qs[32 * LQT];
    __shared__ u16 Ks[128 * LQT];
    __shared__ float redE[128], redR[128], redA[128];
    int cs = blockIdx.x, rt = blockIdx.y, b = blockIdx.z;
    int R0 = rt * 32, C0 = cs * 512;
    int t = threadIdx.x;
    int lane = t & 63, w = t >> 6, q = lane >> 4, r16 = lane & 15;

    const u16* Qg = Qb + ((size_t)b * NN + R0) * DD;
#pragma unroll
    for (int rep = 0; rep < 2; ++rep) {
        int e = rep * 256 + t;
        int row = e >> 4, seg = e & 15;
        *(uint4*)&Qs[row * LQT + seg * 8] = *(const uint4*)&Qg[row * DD + seg * 8];
    }
    const u16* Kg = Kb + (size_t)b * NN * DD;
    float ER[2][4], LR[2][4], LA[2][4];
#pragma unroll
    for (int i = 0; i < 2; ++i)
#pragma unroll
        for (int r = 0; r < 4; ++r) { ER[i][r] = 0.f; LR[i][r] = 0.f; LA[i][r] = 0.f; }

    for (int ct = 0; ct < 4; ++ct) {
        __syncthreads();
#pragma unroll
        for (int rep = 0; rep < 8; ++rep) {       // K tile: 128 cols x 128 k
            int e = rep * 256 + t;
            int colr = e >> 4, seg = e & 15;
            *(uint4*)&Ks[colr * LQT + seg * 8] =
                *(const uint4*)&Kg[(size_t)(C0 + ct * 128 + colr) * DD + seg * 8];
        }
        __syncthreads();
        f32x4 acc[2][2];
#pragma unroll
        for (int i = 0; i < 2; ++i)
#pragma unroll
            for (int j = 0; j < 2; ++j)
                acc[i][j] = (f32x4){0.f, 0.f, 0.f, 0.f};
#pragma unroll
        for (int ksp = 0; ksp < 4; ++ksp) {
            int ko = ksp * 32 + q * 8;
            bf16x8 a0 = *(const bf16x8*)&Qs[r16 * LQT + ko];
            bf16x8 a1 = *(const bf16x8*)&Qs[(16 + r16) * LQT + ko];
            bf16x8 b0 = *(const bf16x8*)&Ks[(w * 32 + r16) * LQT + ko];
            bf16x8 b1 = *(const bf16x8*)&Ks[(w * 32 + 16 + r16) * LQT + ko];
            acc[0][0] = __builtin_amdgcn_mfma_f32_16x16x32_bf16(a0, b0, acc[0][0], 0, 0, 0);
            acc[0][1] = __builtin_amdgcn_mfma_f32_16x16x32_bf16(a0, b1, acc[0][1], 0, 0, 0);
            acc[1][0] = __builtin_amdgcn_mfma_f32_16x16x32_bf16(a1, b0, acc[1][0], 0, 0, 0);
            acc[1][1] = __builtin_amdgcn_mfma_f32_16x16x32_bf16(a1, b1, acc[1][1], 0, 0, 0);
        }
        int m0 = C0 + ct * 128 + w * 32;
        float rm0 = clamp01(rel[b * NN + m0 + r16]);
        float rm1 = clamp01(rel[b * NN + m0 + 16 + r16]);
#pragma unroll
        for (int i = 0; i < 2; ++i)
#pragma unroll
            for (int r = 0; r < 4; ++r) {
                int n = R0 + i * 16 + q * 4 + r;
                const u16* lrow = lgh + (size_t)n * NN + m0;
                const u16* arow = am + (size_t)n * NN + m0;
                float lg0 = h2f(lrow[r16]), lg1 = h2f(lrow[16 + r16]);
                float a0 = bf2f(arow[r16]), a1 = bf2f(arow[16 + r16]);
                u16 eb0 = f2bf(__expf(acc[i][0][r] + lg0));   // masked: -inf -> 0
                u16 eb1 = f2bf(__expf(acc[i][1][r] + lg1));
                size_t o = ((size_t)b * NN + n) * NN + m0;
                Ebuf[o + r16] = eb0;
                Ebuf[o + 16 + r16] = eb1;
                float e0 = bf2f(eb0), e1 = bf2f(eb1);         // sum the ROUNDED e
                ER[i][r] += e0 + e1;
                LR[i][r] = fmaf(e0, rm0, fmaf(e1, rm1, LR[i][r]));
                LA[i][r] = fmaf(a0, rm0, fmaf(a1, rm1, LA[i][r]));
            }
    }
#pragma unroll
    for (int i = 0; i < 2; ++i)
#pragma unroll
        for (int r = 0; r < 4; ++r) {
            float e = ER[i][r], lr = LR[i][r], la = LA[i][r];
#pragma unroll
            for (int off = 1; off < 16; off <<= 1) {
                e += __shfl_xor(e, off);
                lr += __shfl_xor(lr, off);
                la += __shfl_xor(la, off);
            }
            if (r16 == 0) {
                int row = i * 16 + q * 4 + r;
                redE[w * 32 + row] = e;
                redR[w * 32 + row] = lr;
                redA[w * 32 + row] = la;
            }
        }
    __syncthreads();
    if (t < 32) {
        float es = redE[t] + redE[32 + t] + redE[64 + t] + redE[96 + t];
        float lr = redR[t] + redR[32 + t] + redR[64 + t] + redR[96 + t];
        float la = redA[t] + redA[32 + t] + redA[64 + t] + redA[96 + t];
        float* p = part + ((size_t)((b * 64 + rt) * 4 + cs)) * 96;
        p[t] = es;
        p[32 + t] = lr;
        p[64 + t] = la;
    }
}

// ---------------- K4b: per-row coefficients (al, be) ------------------------
__global__ __launch_bounds__(256) void coef_kernel(const float* __restrict__ part,
                                                   const float* __restrict__ rel,
                                                   float2* __restrict__ coef) {
    int rw = blockIdx.x * 256 + threadIdx.x;      // 16384 rows (b*N+n)
    int b = rw >> 11, n = rw & (NN - 1);
    int rt = n >> 5, row = n & 31;
    const float* p = part + ((size_t)((b * 64 + rt) * 4)) * 96;
    float es = 0.f, lr = 0.f, la = 0.f;
#pragma unroll
    for (int cs = 0; cs < 4; ++cs) {
        es += p[cs * 96 + row];
        lr += p[cs * 96 + 32 + row];
        la += p[cs * 96 + 64 + row];
    }
    float rn = clamp01(rel[rw]);
    float inv = 1.f / es;                         // es > 0 (diag edge kept)
    float fsum = rn * (0.6f * lr * inv + 0.4f * la);
    float nrm = 1.f / (fsum + 1e-8f);
    coef[rw] = make_float2(0.6f * inv * rn * nrm, 0.4f * rn * nrm);
}

// ---------------- K5: split-K GEMM1 with fused A_fuse materialization -------
// grid (ks=4, rt=64, b=8). A-staging computes v = rm*(al*e + be*a), writes
// fp32 A_fuse (output) once, packs bf16 into LDS for MFMA. Hp = partials.
#define LPT 72
__global__ __launch_bounds__(256) void prop_kernel(
        const u16* __restrict__ Ebuf, const u16* __restrict__ am,
        const float2* __restrict__ coef, const float* __restrict__ rel,
        const u16* __restrict__ HnT,
        float* __restrict__ Af, float* __restrict__ Hp) {
    __shared__ u16 As[32 * LPT];
    __shared__ u16 Bs[128 * LPT];
    int ks = blockIdx.x, rt = blockIdx.y, b = blockIdx.z;
    int R0 = rt * 32, K0 = ks * 512;
    int t = threadIdx.x;
    int lane = t & 63, w = t >> 6, q = lane >> 4, r16 = lane & 15;
    int srow = t >> 3, sseg = t & 7;
    int n = R0 + srow;
    float2 cf = coef[b * NN + n];
    const u16* Eg = Ebuf + ((size_t)b * NN + n) * NN;
    const u16* ag = am + (size_t)n * NN;
    const float* rg = rel + b * NN;
    const u16* Bg = HnT + (size_t)b * DD * NN;
    float* Afg = Af + ((size_t)b * NN + n) * NN;

    f32x4 acc[2][2];
#pragma unroll
    for (int i = 0; i < 2; ++i)
#pragma unroll
        for (int j = 0; j < 2; ++j)
            acc[i][j] = (f32x4){0.f, 0.f, 0.f, 0.f};

    for (int kc = K0; kc < K0 + 512; kc += 64) {
        __syncthreads();
        {   // A stage + materialize (each thread: row srow, 8 cols)
            int m = kc + sseg * 8;
            uint4 ev = *(const uint4*)&Eg[m];
            uint4 av = *(const uint4*)&ag[m];
            float4 r0 = *(const float4*)&rg[m];
            float4 r1 = *(const float4*)&rg[m + 4];
            unsigned eu[4] = {ev.x, ev.y, ev.z, ev.w};
            unsigned au[4] = {av.x, av.y, av.z, av.w};
            float rm[8] = {clamp01(r0.x), clamp01(r0.y), clamp01(r0.z), clamp01(r0.w),
                           clamp01(r1.x), clamp01(r1.y), clamp01(r1.z), clamp01(r1.w)};
            float v[8];
            unsigned pk[4];
#pragma unroll
            for (int j = 0; j < 4; ++j) {
                float e0 = bf2f((u16)(eu[j] & 0xffff));
                float e1 = bf2f((u16)(eu[j] >> 16));
                float a0 = bf2f((u16)(au[j] & 0xffff));
                float a1 = bf2f((u16)(au[j] >> 16));
                v[2 * j] = rm[2 * j] * fmaf(e0, cf.x, a0 * cf.y);
                v[2 * j + 1] = rm[2 * j + 1] * fmaf(e1, cf.x, a1 * cf.y);
                pk[j] = (unsigned)f2bf(v[2 * j]) | ((unsigned)f2bf(v[2 * j + 1]) << 16);
            }
            *(float4*)&Afg[m] = make_float4(v[0], v[1], v[2], v[3]);
            *(float4*)&Afg[m + 4] = make_float4(v[4], v[5], v[6], v[7]);
            *(uint4*)&As[srow * LPT + sseg * 8] = make_uint4(pk[0], pk[1], pk[2], pk[3]);
        }
#pragma unroll
        for (int rep = 0; rep < 4; ++rep) {       // B stage: 128 d x 64 m
            int e = rep * 256 + t;
            int d = e >> 3, sg = e & 7;
            *(uint4*)&Bs[d * LPT + sg * 8] =
                *(const uint4*)&Bg[(size_t)d * NN + kc + sg * 8];
        }
        __syncthreads();
#pragma unroll
        for (int kst = 0; kst < 2; ++kst) {
            int ko = kst * 32 + q * 8;
            bf16x8 a0 = *(const bf16x8*)&As[r16 * LPT + ko];
            bf16x8 a1 = *(const bf16x8*)&As[(16 + r16) * LPT + ko];
            bf16x8 b0 = *(const bf16x8*)&Bs[(w * 32 + r16) * LPT + ko];
            bf16x8 b1v = *(const bf16x8*)&Bs[(w * 32 + 16 + r16) * LPT + ko];
            acc[0][0] = __builtin_amdgcn_mfma_f32_16x16x32_bf16(a0, b0, acc[0][0], 0, 0, 0);
            acc[0][1] = __builtin_amdgcn_mfma_f32_16x16x32_bf16(a0, b1v, acc[0][1], 0, 0, 0);
            acc[1][0] = __builtin_amdgcn_mfma_f32_16x16x32_bf16(a1, b0, acc[1][0], 0, 0, 0);
            acc[1][1] = __builtin_amdgcn_mfma_f32_16x16x32_bf16(a1, b1v, acc[1][1], 0, 0, 0);
        }
    }
    float* Hg = Hp + (((size_t)ks * BB + b) * NN + R0) * DD;
#pragma unroll
    for (int i = 0; i < 2; ++i)
#pragma unroll
        for (int j = 0; j < 2; ++j)
#pragma unroll
            for (int r = 0; r < 4; ++r)
                Hg[(size_t)(i * 16 + q * 4 + r) * DD + w * 32 + j * 16 + r16] = acc[i][j][r];
}

// ---------------- K6: sum partials -> @W_lin -> relu -> LN1 -> LN2 ---------
#define LWT 136
__global__ __launch_bounds__(256) void final_kernel(
        const float* __restrict__ Hp, const u16* __restrict__ WlT,
        const float* __restrict__ s1, const float* __restrict__ b1,
        const float* __restrict__ s2, const float* __restrict__ b2,
        float* __restrict__ out) {
    __shared__ u16 Ws[128 * LWT];
    __shared__ u16 Hs[32 * LWT];
    __shared__ float redS[128], redQ[128];
    __shared__ float2 MV[32];
    int G0 = blockIdx.x * 32;                     // flattened row base (b*N+n)
    int t = threadIdx.x;
    int lane = t & 63, w = t >> 6, q = lane >> 4, r16 = lane & 15;

#pragma unroll
    for (int rep = 0; rep < 8; ++rep) {
        int e = rep * 256 + t;
        int dp = e >> 4, seg = e & 15;
        *(uint4*)&Ws[dp * LWT + seg * 8] = *(const uint4*)&WlT[dp * DD + seg * 8];
    }
    const size_t PS = (size_t)BB * NN * DD;
#pragma unroll
    for (int rep = 0; rep < 2; ++rep) {           // sum 4 partials -> bf16 LDS
        int e = rep * 256 + t;
        int row = e >> 4, seg = e & 15;
        const float* hb = Hp + (size_t)(G0 + row) * DD + seg * 8;
        float4 x0 = *(const float4*)&hb[0];
        float4 x1 = *(const float4*)&hb[4];
#pragma unroll
        for (int s = 1; s < 4; ++s) {
            float4 y0 = *(const float4*)&hb[s * PS];
            float4 y1 = *(const float4*)&hb[s * PS + 4];
            x0.x += y0.x; x0.y += y0.y; x0.z += y0.z; x0.w += y0.w;
            x1.x += y1.x; x1.y += y1.y; x1.z += y1.z; x1.w += y1.w;
        }
        unsigned pk[4];
        pk[0] = (unsigned)f2bf(x0.x) | ((unsigned)f2bf(x0.y) << 16);
        pk[1] = (unsigned)f2bf(x0.z) | ((unsigned)f2bf(x0.w) << 16);
        pk[2] = (unsigned)f2bf(x1.x) | ((unsigned)f2bf(x1.y) << 16);
        pk[3] = (unsigned)f2bf(x1.z) | ((unsigned)f2bf(x1.w) << 16);
        *(uint4*)&Hs[row * LWT + seg * 8] = make_uint4(pk[0], pk[1], pk[2], pk[3]);
    }
    __syncthreads();

    f32x4 c2[2][2];
#pragma unroll
    for (int i = 0; i < 2; ++i)
#pragma unroll
        for (int j = 0; j < 2; ++j)
            c2[i][j] = (f32x4){0.f, 0.f, 0.f, 0.f};
#pragma unroll
    for (int ksp = 0; ksp < 4; ++ksp) {
        int ko = ksp * 32 + q * 8;
        bf16x8 a0 = *(const bf16x8*)&Hs[r16 * LWT + ko];
        bf16x8 a1 = *(const bf16x8*)&Hs[(16 + r16) * LWT + ko];
        bf16x8 b0 = *(const bf16x8*)&Ws[(w * 32 + r16) * LWT + ko];
        bf16x8 b1v = *(const bf16x8*)&Ws[(w * 32 + 16 + r16) * LWT + ko];
        c2[0][0] = __builtin_amdgcn_mfma_f32_16x16x32_bf16(a0, b0, c2[0][0], 0, 0, 0);
        c2[0][1] = __builtin_amdgcn_mfma_f32_16x16x32_bf16(a0, b1v, c2[0][1], 0, 0, 0);
        c2[1][0] = __builtin_amdgcn_mfma_f32_16x16x32_bf16(a1, b0, c2[1][0], 0, 0, 0);
        c2[1][1] = __builtin_amdgcn_mfma_f32_16x16x32_bf16(a1, b1v, c2[1][1], 0, 0, 0);
    }
    float v[2][2][4];
#pragma unroll
    for (int i = 0; i < 2; ++i)
#pragma unroll
        for (int j = 0; j < 2; ++j)
#pragma unroll
            for (int r = 0; r < 4; ++r)
                v[i][j][r] = fmaxf(c2[i][j][r], 0.f);

    int c0 = w * 32 + r16, c1 = w * 32 + 16 + r16;
    float s1c0 = s1[c0], s1c1 = s1[c1], b1c0 = b1[c0], b1c1 = b1[c1];
    float s2c0 = s2[c0], s2c1 = s2[c1], b2c0 = b2[c0], b2c1 = b2[c1];

#pragma unroll
    for (int i = 0; i < 2; ++i)
#pragma unroll
        for (int r = 0; r < 4; ++r) {
            float s = v[i][0][r] + v[i][1][r];
            float qq = v[i][0][r] * v[i][0][r] + v[i][1][r] * v[i][1][r];
#pragma unroll
            for (int off = 1; off < 16; off <<= 1) {
                s += __shfl_xor(s, off);
                qq += __shfl_xor(qq, off);
            }
            if (r16 == 0) {
                int row = i * 16 + q * 4 + r;
                redS[w * 32 + row] = s;
                redQ[w * 32 + row] = qq;
            }
        }
    __syncthreads();
    if (t < 32) {
        float s = redS[t] + redS[32 + t] + redS[64 + t] + redS[96 + t];
        float qq = redQ[t] + redQ[32 + t] + redQ[64 + t] + redQ[96 + t];
        float mu = s * (1.f / 128.f);
        float var = qq * (1.f / 128.f) - mu * mu;
        MV[t] = make_float2(mu, 1.f / sqrtf(var + 1e-5f));
    }
    __syncthreads();
    float y[2][2][4];
#pragma unroll
    for (int i = 0; i < 2; ++i)
#pragma unroll
        for (int r = 0; r < 4; ++r) {
            float2 mv = MV[i * 16 + q * 4 + r];
            y[i][0][r] = (v[i][0][r] - mv.x) * mv.y * s1c0 + b1c0;
            y[i][1][r] = (v[i][1][r] - mv.x) * mv.y * s1c1 + b1c1;
        }
    __syncthreads();
#pragma unroll
    for (int i = 0; i < 2; ++i)
#pragma unroll
        for (int r = 0; r < 4; ++r) {
            float s = y[i][0][r] + y[i][1][r];
            float qq = y[i][0][r] * y[i][0][r] + y[i][1][r] * y[i][1][r];
#pragma unroll
            for (int off = 1; off < 16; off <<= 1) {
                s += __shfl_xor(s, off);
                qq += __shfl_xor(qq, off);
            }
            if (r16 == 0) {
                int row = i * 16 + q * 4 + r;
                redS[w * 32 + row] = s;
                redQ[w * 32 + row] = qq;
            }
        }
    __syncthreads();
    if (t < 32) {
        float s = redS[t] + redS[32 + t] + redS[64 + t] + redS[96 + t];
        float qq = redQ[t] + redQ[32 + t] + redQ[64 + t] + redQ[96 + t];
        float mu = s * (1.f / 128.f);
        float var = qq * (1.f / 128.f) - mu * mu;
        MV[t] = make_float2(mu, 1.f / sqrtf(var + 1e-5f));
    }
    __syncthreads();
#pragma unroll
    for (int i = 0; i < 2; ++i)
#pragma unroll
        for (int r = 0; r < 4; ++r) {
            float2 mv = MV[i * 16 + q * 4 + r];
            size_t o = (size_t)(G0 + i * 16 + q * 4 + r) * DD;
            out[o + c0] = (y[i][0][r] - mv.x) * mv.y * s2c0 + b2c0;
            out[o + c1] = (y[i][1][r] - mv.x) * mv.y * s2c1 + b2c1;
        }
}

extern "C" void kernel_launch(void* const* d_in, const int* in_sizes, int n_in,
                              void* d_out, int out_size, void* d_ws, size_t ws_size,
                              hipStream_t stream) {
    const float* X = (const float*)d_in[0];
    const float* Msk = (const float*)d_in[1];
    const float* Astat = (const float*)d_in[2];
    const int* Mm = (const int*)d_in[3];
    const float* rel = (const float*)d_in[4];
    const float* Wproj = (const float*)d_in[5];
    const float* Wq = (const float*)d_in[6];
    const float* Wk = (const float*)d_in[7];
    const float* Wlin = (const float*)d_in[8];
    const float* s1 = (const float*)d_in[9];
    const float* b1 = (const float*)d_in[10];
    const float* s2 = (const float*)d_in[11];
    const float* b2 = (const float*)d_in[12];

    float* outMain = (float*)d_out;                       // (B,N,D)
    float* Afuse = outMain + (size_t)BB * NN * DD;        // (B,N,N)

    float* w_ = (float*)d_ws;
    float* x = w_;                                        // 524288
    float* Wpq = w_ + 524288;                             // 4096
    float* Wpk = w_ + 528384;                             // 4096
    u16* WlT = (u16*)(w_ + 532480);                       // 16384 u16
    u16* Qb = (u16*)(w_ + 540672);                        // 2097152 u16
    u16* Kb = (u16*)(w_ + 1589248);
    u16* HnT = (u16*)(w_ + 2637824);
    u16* lgh = (u16*)(w_ + 3686400);                      // 4194304 u16 (f16)
    u16* am = (u16*)(w_ + 5783552);                       // 4194304 u16 (bf16)
    u16* Ebuf = (u16*)(w_ + 7880704);                     // 33554432 u16 (bf16)
    float* part = w_ + 24657920;                          // 196608 f
    float2* coef = (float2*)(w_ + 24854528);              // 16384 float2
    float* Hp = w_ + 24887296;                            // 4 x 2097152 f

    pool_kernel<<<dim3(2048), dim3(256), 0, stream>>>(X, Msk, x);
    wcomb_kernel<<<dim3(32), dim3(256), 0, stream>>>(Wproj, Wq, Wk, Wpq, Wpk);
    wlt_kernel<<<dim3(64), dim3(256), 0, stream>>>(Wlin, WlT);
    bias_prep_kernel<<<dim3(4096), dim3(256), 0, stream>>>(Astat, Mm, lgh, am);
    proj3_kernel<<<dim3(512), dim3(256), 0, stream>>>(x, Wproj, Wpq, Wpk, HnT, Qb, Kb);

    stats_kernel<<<dim3(4, 64, 8), dim3(256), 0, stream>>>(
        Qb, Kb, lgh, am, rel, Ebuf, part);
    coef_kernel<<<dim3(64), dim3(256), 0, stream>>>(part, rel, coef);
    prop_kernel<<<dim3(4, 64, 8), dim3(256), 0, stream>>>(
        Ebuf, am, coef, rel, HnT, Afuse, Hp);
    final_kernel<<<dim3(512), dim3(256), 0, stream>>>(
        Hp, WlT, s1, b1, s2, b2, outMain);
}